// Round 9
// baseline (264.331 us; speedup 1.0000x reference)
//
// PointNet++ FP: three_nn + three_interpolate + pointwise MLP(384->256->128)
// Round 9: software-pipelined persistent blocks. 512 blocks x 2 tiles (64 pts
// each). The gather of tile t (48 long-latency vector loads) is interleaved
// IN THE SAME LOOP with the scan of tile t+1 (~8K VALU ops): scan fills the
// gather's load shadow (vmcnt vs lgkmcnt are independent). r8's merge showed
// 64us scan-VALU + 80us idle-VALU phases; this folds them.
// LDS: Xs/Y1 overlay 50176 + sd/si 6144 (own region now - concurrent with Xs
// writes) + iw double-buffer 3072 = 59392 B -> 2 blocks/CU; grid 512 = 2/CU.
// MFMA 16x16x32 bf16 layouts (learn_hip m89/m120 verified):
//   A: [m=lane&15][k=(lane>>4)*8+j]   B: [k=(lane>>4)*8+j][n=lane&15]
//   D: [row=(lane>>4)*4+reg][col=lane&15]
#include <hip/hip_runtime.h>

typedef __bf16 bf16_t;
typedef bf16_t bf16x2_t __attribute__((ext_vector_type(2)));
typedef bf16_t bf16x4_t __attribute__((ext_vector_type(4)));
typedef bf16_t bf16x8_t __attribute__((ext_vector_type(8)));
typedef float floatx4_t __attribute__((ext_vector_type(4)));

constexpr int B_ = 8, N_ = 8192, M_ = 2048;
constexpr int C1 = 128, C2 = 256;
constexpr int K1 = 384, N1 = 256, N2 = 128;

// ws layout (bytes)
constexpr size_t WS_W1T   = 0;         // bf16  [256][384]  = 196608 B
constexpr size_t WS_W2T   = 196608;    // bf16  [128][256]  =  65536 B
constexpr size_t WS_XYZ2P = 262144;    // float4[8*2048]    = 262144 B

// ---------------------------------------------------------------- prep ----
__global__ __launch_bounds__(256) void prep_kernel(
    const float* __restrict__ W1, const float* __restrict__ W2,
    const float* __restrict__ xyz2,
    bf16_t* __restrict__ W1T, bf16_t* __restrict__ W2T,
    float4* __restrict__ xyz2p) {
  int bid = blockIdx.x, tid = threadIdx.x;
  if (bid < 384) {                       // W1 [384][256] -> W1T [256][384]
    int t = bid * 256 + tid;             // 98304 elems
    int n = t / K1, k = t - n * K1;
    W1T[t] = (bf16_t)W1[k * N1 + n];
  } else if (bid < 512) {                // W2 [256][128] -> W2T [128][256]
    int t = (bid - 384) * 256 + tid;     // 32768 elems
    int n = t / N1, k = t - n * N1;
    W2T[t] = (bf16_t)W2[k * N2 + n];
  } else {                               // xyz2 -> float4{x,y,z,|q|^2}
    int t = (bid - 512) * 256 + tid;     // 16384 elems
    const float* p = xyz2 + (size_t)t * 3;
    float x = p[0], y = p[1], z = p[2];
    xyz2p[t] = make_float4(x, y, z, x * x + y * y + z * z);
  }
}

// ---------------------------------------------- fused nn+interp+MLP -------
// 512 blocks x 256 threads; block bi owns tiles bi and bi+512 (both batch
// b = bi&7 -> XCD-local points2 slice). Pipeline per tile t:
//   [gather(t) || scan(t+1)] -> sd/si -> sync -> fold(iw) | L1-MFMA(t)
//   -> sync -> relu->Y1 -> sync -> L2-MFMA(t)->out -> sync
__global__ __launch_bounds__(256, 2) void fp_fused_kernel(
    const float* __restrict__ xyz1, const float4* __restrict__ xyz2p,
    const float* __restrict__ points1, const float* __restrict__ points2,
    const bf16_t* __restrict__ W1T, const float* __restrict__ b1,
    const bf16_t* __restrict__ W2T, const float* __restrict__ b2,
    float* __restrict__ out) {
  __shared__ __align__(16) char smem[64 * 392 * 2];   // 50176 B (Xs / Y1)
  __shared__ float sd[4][64][3];                      // 3072 B scan partials
  __shared__ int   si[4][64][3];                      // 3072 B
  __shared__ int   iwI[2][64][3];                     // 1536 B (dbuf)
  __shared__ float iwW[2][64][3];                     // 1536 B
  bf16_t (*Xs)[392] = (bf16_t(*)[392])smem;
  bf16_t (*Y1)[264] = (bf16_t(*)[264])smem;

  int bi = blockIdx.x;             // 0..511
  int b = bi & 7;                  // XCD-aware batch
  int tid = threadIdx.x;
  int wave = __builtin_amdgcn_readfirstlane(tid >> 6);  // 0..3
  int lane = tid & 63;
  int q = lane >> 4, r = lane & 15;

  const float4* p2 = xyz2p + b * M_ + (wave << 9);  // wave chunk (constant)
  int jbase = wave << 9;

  // ---- scan state (registers, live across the combined loop) ----
  float cd0[4], cd1[4], cd2[4];
  int   ci0[4], ci1[4], ci2[4];
  float sm2x, sm2y, sm2z, ssq1;

  auto scan_init = [&](int sbase) {
    const float* p1 = xyz1 + ((size_t)b * N_ + sbase + lane) * 3;
    float x = p1[0], y = p1[1], z = p1[2];
    ssq1 = x * x + y * y + z * z;
    sm2x = -2.0f * x; sm2y = -2.0f * y; sm2z = -2.0f * z;
#pragma unroll
    for (int t = 0; t < 4; ++t) {
      cd0[t] = 1e30f; cd1[t] = 1e30f; cd2[t] = 1e30f;
      ci0[t] = 0; ci1[t] = 0; ci2[t] = 0;
    }
  };
  auto scan32 = [&](int j0) {      // 32 candidates starting at chunk-offset j0
#pragma unroll
    for (int g = 0; g < 32; g += 4) {
#pragma unroll
      for (int t = 0; t < 4; ++t) {
        float4 qv = p2[j0 + g + t];
        int jj = jbase + j0 + g + t;
        float d = fmaf(sm2x, qv.x, fmaf(sm2y, qv.y, fmaf(sm2z, qv.z, qv.w)));
        bool l0 = d < cd0[t], l1 = d < cd1[t], l2 = d < cd2[t];
        float n0v = fminf(cd0[t], d);
        float n1v = __builtin_amdgcn_fmed3f(d, cd0[t], cd1[t]);
        float n2v = __builtin_amdgcn_fmed3f(d, cd1[t], cd2[t]);
        int t1 = l0 ? ci0[t] : jj;
        int t2 = l1 ? ci1[t] : jj;
        ci0[t] = l0 ? jj : ci0[t];
        ci1[t] = l1 ? t1 : ci1[t];
        ci2[t] = l2 ? t2 : ci2[t];
        cd0[t] = n0v; cd1[t] = n1v; cd2[t] = n2v;
      }
    }
  };
  auto scan_fin = [&]() {          // merge 4 chains -> sd/si[wave][lane]
    float s0 = cd0[0], s1 = cd1[0], s2 = cd2[0];
    int i0 = ci0[0], i1 = ci1[0], i2 = ci2[0];
    auto ins = [&](float d, int j) {
      if (d < s2) {
        if (d < s1) {
          s2 = s1; i2 = i1;
          if (d < s0) { s1 = s0; i1 = i0; s0 = d; i0 = j; }
          else        { s1 = d;  i1 = j; }
        } else { s2 = d; i2 = j; }
      }
    };
#pragma unroll
    for (int t = 1; t < 4; ++t) {
      ins(cd0[t], ci0[t]); ins(cd1[t], ci1[t]); ins(cd2[t], ci2[t]);
    }
    sd[wave][lane][0] = s0 + ssq1; si[wave][lane][0] = i0;
    sd[wave][lane][1] = s1 + ssq1; si[wave][lane][1] = i1;
    sd[wave][lane][2] = s2 + ssq1; si[wave][lane][2] = i2;
  };
  auto fold = [&](int buf) {       // wave0: 4 partials -> iw[buf]
    if (tid < 64) {
      float t0 = sd[0][tid][0], t1 = sd[0][tid][1], t2 = sd[0][tid][2];
      int   a0 = si[0][tid][0], a1 = si[0][tid][1], a2 = si[0][tid][2];
#pragma unroll
      for (int cc = 1; cc < 4; ++cc) {
#pragma unroll
        for (int k = 0; k < 3; ++k) {
          float d = sd[cc][tid][k];
          int   j = si[cc][tid][k];
          if (d < t2) {
            if (d < t1) {
              t2 = t1; a2 = a1;
              if (d < t0) { t1 = t0; a1 = a0; t0 = d; a0 = j; }
              else        { t1 = d;  a1 = j; }
            } else { t2 = d; a2 = j; }
          }
        }
      }
      float e0 = fmaxf(t0, 1e-10f), e1 = fmaxf(t1, 1e-10f), e2 = fmaxf(t2, 1e-10f);
      float r0 = 1.0f / e0, r1 = 1.0f / e1, r2 = 1.0f / e2;
      float rs = 1.0f / (r0 + r1 + r2);
      iwI[buf][tid][0] = a0; iwI[buf][tid][1] = a1; iwI[buf][tid][2] = a2;
      iwW[buf][tid][0] = r0 * rs; iwW[buf][tid][1] = r1 * rs; iwW[buf][tid][2] = r2 * rs;
    }
  };
  auto gather_iter = [&](int i, int buf, size_t bN) {
    int p = wave * 16 + i;                       // uniform per iteration
    int j0 = __builtin_amdgcn_readfirstlane(iwI[buf][p][0]);
    int j1 = __builtin_amdgcn_readfirstlane(iwI[buf][p][1]);
    int j2 = __builtin_amdgcn_readfirstlane(iwI[buf][p][2]);
    float w0 = iwW[buf][p][0], w1 = iwW[buf][p][1], w2 = iwW[buf][p][2];
    const float* g0 = points2 + ((size_t)b * M_ + j0) * C2;
    const float* g1 = points2 + ((size_t)b * M_ + j1) * C2;
    const float* g2 = points2 + ((size_t)b * M_ + j2) * C2;
    int c4 = lane * 4;
    float4 a0 = *(const float4*)(g0 + c4);
    float4 a1 = *(const float4*)(g1 + c4);
    float4 a2 = *(const float4*)(g2 + c4);
    const float* pp1 = points1 + (bN + p) * C1;
    float2 s = *(const float2*)(pp1 + lane * 2);
    bf16x4_t v;
    v[0] = (bf16_t)(w0 * a0.x + w1 * a1.x + w2 * a2.x);
    v[1] = (bf16_t)(w0 * a0.y + w1 * a1.y + w2 * a2.y);
    v[2] = (bf16_t)(w0 * a0.z + w1 * a1.z + w2 * a2.z);
    v[3] = (bf16_t)(w0 * a0.w + w1 * a1.w + w2 * a2.w);
    *(bf16x4_t*)(&Xs[p][c4]) = v;
    bf16x2_t v2; v2[0] = (bf16_t)s.x; v2[1] = (bf16_t)s.y;
    *(bf16x2_t*)(&Xs[p][256 + lane * 2]) = v2;
  };

  // ================= prologue: scan tile 0 ================================
  int base0 = (bi >> 3) * 64;
  int base1 = ((bi + 512) >> 3) * 64;
  scan_init(base0);
  for (int i = 0; i < 16; ++i) scan32(i * 32);
  scan_fin();
  __syncthreads();
  fold(0);
  __syncthreads();

  // ================= tile loop (2 tiles) ==================================
  for (int tt = 0; tt < 2; ++tt) {
    int bcur = tt ? base1 : base0;
    size_t bN = (size_t)b * N_ + bcur;
    bool hn = (tt == 0);

    // ---- combined: gather(t) fills load shadow with scan(t+1) VALU ----
    if (hn) scan_init(base1);
    for (int i = 0; i < 16; ++i) {
      gather_iter(i, tt, bN);
      if (hn) scan32(i * 32);
    }
    if (hn) scan_fin();
    __syncthreads();                 // Xs complete; sd/si(t+1) published
    if (hn) fold(1);                 // wave0; others proceed to L1

    // ---- Layer 1: [64 x 384] x [384 x 256] -> acc, wave owns 64 cols ----
    floatx4_t acc[4][4] = {};
    const bf16_t* wp0 = W1T + (size_t)(wave * 64 +  0 + r) * K1;
    const bf16_t* wp1 = W1T + (size_t)(wave * 64 + 16 + r) * K1;
    const bf16_t* wp2 = W1T + (size_t)(wave * 64 + 32 + r) * K1;
    const bf16_t* wp3 = W1T + (size_t)(wave * 64 + 48 + r) * K1;
    for (int kk = 0; kk < 12; ++kk) {
      int k0 = kk * 32 + q * 8;
      bf16x8_t a0 = *(const bf16x8_t*)(&Xs[ 0 + r][k0]);
      bf16x8_t a1 = *(const bf16x8_t*)(&Xs[16 + r][k0]);
      bf16x8_t a2 = *(const bf16x8_t*)(&Xs[32 + r][k0]);
      bf16x8_t a3 = *(const bf16x8_t*)(&Xs[48 + r][k0]);
      bf16x8_t bb0 = *(const bf16x8_t*)(wp0 + k0);
      bf16x8_t bb1 = *(const bf16x8_t*)(wp1 + k0);
      bf16x8_t bb2 = *(const bf16x8_t*)(wp2 + k0);
      bf16x8_t bb3 = *(const bf16x8_t*)(wp3 + k0);
      acc[0][0] = __builtin_amdgcn_mfma_f32_16x16x32_bf16(a0, bb0, acc[0][0], 0, 0, 0);
      acc[1][0] = __builtin_amdgcn_mfma_f32_16x16x32_bf16(a1, bb0, acc[1][0], 0, 0, 0);
      acc[2][0] = __builtin_amdgcn_mfma_f32_16x16x32_bf16(a2, bb0, acc[2][0], 0, 0, 0);
      acc[3][0] = __builtin_amdgcn_mfma_f32_16x16x32_bf16(a3, bb0, acc[3][0], 0, 0, 0);
      acc[0][1] = __builtin_amdgcn_mfma_f32_16x16x32_bf16(a0, bb1, acc[0][1], 0, 0, 0);
      acc[1][1] = __builtin_amdgcn_mfma_f32_16x16x32_bf16(a1, bb1, acc[1][1], 0, 0, 0);
      acc[2][1] = __builtin_amdgcn_mfma_f32_16x16x32_bf16(a2, bb1, acc[2][1], 0, 0, 0);
      acc[3][1] = __builtin_amdgcn_mfma_f32_16x16x32_bf16(a3, bb1, acc[3][1], 0, 0, 0);
      acc[0][2] = __builtin_amdgcn_mfma_f32_16x16x32_bf16(a0, bb2, acc[0][2], 0, 0, 0);
      acc[1][2] = __builtin_amdgcn_mfma_f32_16x16x32_bf16(a1, bb2, acc[1][2], 0, 0, 0);
      acc[2][2] = __builtin_amdgcn_mfma_f32_16x16x32_bf16(a2, bb2, acc[2][2], 0, 0, 0);
      acc[3][2] = __builtin_amdgcn_mfma_f32_16x16x32_bf16(a3, bb2, acc[3][2], 0, 0, 0);
      acc[0][3] = __builtin_amdgcn_mfma_f32_16x16x32_bf16(a0, bb3, acc[0][3], 0, 0, 0);
      acc[1][3] = __builtin_amdgcn_mfma_f32_16x16x32_bf16(a1, bb3, acc[1][3], 0, 0, 0);
      acc[2][3] = __builtin_amdgcn_mfma_f32_16x16x32_bf16(a2, bb3, acc[2][3], 0, 0, 0);
      acc[3][3] = __builtin_amdgcn_mfma_f32_16x16x32_bf16(a3, bb3, acc[3][3], 0, 0, 0);
    }
    __syncthreads();   // all layer-1 Xs reads done (fold also done)

    // bias + relu -> Y1 (bf16, overlays Xs)
#pragma unroll
    for (int rt = 0; rt < 4; ++rt) {
#pragma unroll
      for (int ct = 0; ct < 4; ++ct) {
        int nn = wave * 64 + ct * 16 + r;
        float bias = b1[nn];
#pragma unroll
        for (int reg = 0; reg < 4; ++reg) {
          int m = rt * 16 + q * 4 + reg;
          Y1[m][nn] = (bf16_t)fmaxf(acc[rt][ct][reg] + bias, 0.0f);
        }
      }
    }
    __syncthreads();

    // ---- Layer 2: [64 x 256] x [256 x 128] -> out, wave owns 32 cols ----
    floatx4_t acc2[4][2] = {};
    const bf16_t* vp0 = W2T + (size_t)(wave * 32 +  0 + r) * N1;
    const bf16_t* vp1 = W2T + (size_t)(wave * 32 + 16 + r) * N1;
    for (int kk = 0; kk < 8; ++kk) {
      int k0 = kk * 32 + q * 8;
      bf16x8_t a0 = *(const bf16x8_t*)(&Y1[ 0 + r][k0]);
      bf16x8_t a1 = *(const bf16x8_t*)(&Y1[16 + r][k0]);
      bf16x8_t a2 = *(const bf16x8_t*)(&Y1[32 + r][k0]);
      bf16x8_t a3 = *(const bf16x8_t*)(&Y1[48 + r][k0]);
      bf16x8_t bb0 = *(const bf16x8_t*)(vp0 + k0);
      bf16x8_t bb1 = *(const bf16x8_t*)(vp1 + k0);
      acc2[0][0] = __builtin_amdgcn_mfma_f32_16x16x32_bf16(a0, bb0, acc2[0][0], 0, 0, 0);
      acc2[1][0] = __builtin_amdgcn_mfma_f32_16x16x32_bf16(a1, bb0, acc2[1][0], 0, 0, 0);
      acc2[2][0] = __builtin_amdgcn_mfma_f32_16x16x32_bf16(a2, bb0, acc2[2][0], 0, 0, 0);
      acc2[3][0] = __builtin_amdgcn_mfma_f32_16x16x32_bf16(a3, bb0, acc2[3][0], 0, 0, 0);
      acc2[0][1] = __builtin_amdgcn_mfma_f32_16x16x32_bf16(a0, bb1, acc2[0][1], 0, 0, 0);
      acc2[1][1] = __builtin_amdgcn_mfma_f32_16x16x32_bf16(a1, bb1, acc2[1][1], 0, 0, 0);
      acc2[2][1] = __builtin_amdgcn_mfma_f32_16x16x32_bf16(a2, bb1, acc2[2][1], 0, 0, 0);
      acc2[3][1] = __builtin_amdgcn_mfma_f32_16x16x32_bf16(a3, bb1, acc2[3][1], 0, 0, 0);
    }
#pragma unroll
    for (int rt = 0; rt < 4; ++rt) {
#pragma unroll
      for (int ct = 0; ct < 2; ++ct) {
        int cc = wave * 32 + ct * 16 + r;
        float bias = b2[cc];
#pragma unroll
        for (int reg = 0; reg < 4; ++reg) {
          int m = rt * 16 + q * 4 + reg;
          out[(bN + m) * N2 + cc] = fmaxf(acc2[rt][ct][reg] + bias, 0.0f);
        }
      }
    }
    __syncthreads();   // Y1 reads done before next tile's gather writes Xs
  }
}

// ----------------------------------------------------------------- launch --
extern "C" void kernel_launch(void* const* d_in, const int* in_sizes, int n_in,
                              void* d_out, int out_size, void* d_ws, size_t ws_size,
                              hipStream_t stream) {
  (void)in_sizes; (void)n_in; (void)out_size; (void)ws_size;
  const float* xyz1    = (const float*)d_in[0];
  const float* xyz2    = (const float*)d_in[1];
  const float* points1 = (const float*)d_in[2];
  const float* points2 = (const float*)d_in[3];
  const float* W1      = (const float*)d_in[4];
  const float* b1      = (const float*)d_in[5];
  const float* W2      = (const float*)d_in[6];
  const float* b2      = (const float*)d_in[7];
  float* out = (float*)d_out;
  char* ws = (char*)d_ws;
  bf16_t* W1T   = (bf16_t*)(ws + WS_W1T);
  bf16_t* W2T   = (bf16_t*)(ws + WS_W2T);
  float4* xyz2p = (float4*)(ws + WS_XYZ2P);

  prep_kernel<<<576, 256, 0, stream>>>(W1, W2, xyz2, W1T, W2T, xyz2p);
  fp_fused_kernel<<<512, 256, 0, stream>>>(xyz1, xyz2p, points1, points2,
                                           W1T, b1, W2T, b2, out);
}